// Round 2
// 476.110 us; speedup vs baseline: 1.0049x; 1.0049x over previous
//
#include <hip/hip_runtime.h>
#include <cfloat>

#define BLK 256
#define RED_BLOCKS 256
#define NCHUNK 10   // t-chunks per (b,segment); T=100 -> 10 t's per block

// ---------------- Kernel 1: per-block min/max partials ----------------
__global__ void k_minmax_partial(const float* __restrict__ x, int n4,
                                 float* __restrict__ partial) {
    const float4* __restrict__ x4 = (const float4*)x;
    float mn = FLT_MAX, mx = -FLT_MAX;
    for (int i = blockIdx.x * blockDim.x + threadIdx.x; i < n4;
         i += gridDim.x * blockDim.x) {
        float4 v = x4[i];
        mn = fminf(mn, fminf(fminf(v.x, v.y), fminf(v.z, v.w)));
        mx = fmaxf(mx, fmaxf(fmaxf(v.x, v.y), fmaxf(v.z, v.w)));
    }
    for (int off = 32; off > 0; off >>= 1) {
        mn = fminf(mn, __shfl_down(mn, off, 64));
        mx = fmaxf(mx, __shfl_down(mx, off, 64));
    }
    __shared__ float smn[BLK / 64], smx[BLK / 64];
    int lane = threadIdx.x & 63;
    int w = threadIdx.x >> 6;
    if (lane == 0) { smn[w] = mn; smx[w] = mx; }
    __syncthreads();
    if (threadIdx.x == 0) {
        mn = smn[0]; mx = smx[0];
        for (int j = 1; j < BLK / 64; ++j) {
            mn = fminf(mn, smn[j]);
            mx = fmaxf(mx, smx[j]);
        }
        partial[2 * blockIdx.x]     = mn;
        partial[2 * blockIdx.x + 1] = mx;
    }
}

// ---- Kernel 2: fused final-reduce + spike-time -> uint8 array ----
// Every block independently reduces the 256 (mn,mx) pairs (deterministic,
// identical order in all blocks), then computes its slice of spike times.
__global__ void k_spiketime(const float* __restrict__ x,
                            const float* __restrict__ partial,
                            const int* __restrict__ Tptr,
                            unsigned char* __restrict__ st, int n4) {
    __shared__ float smn[BLK / 64], smx[BLK / 64];
    __shared__ float sparams[2];
    {
        float mn = partial[2 * threadIdx.x];
        float mx = partial[2 * threadIdx.x + 1];
        for (int off = 32; off > 0; off >>= 1) {
            mn = fminf(mn, __shfl_down(mn, off, 64));
            mx = fmaxf(mx, __shfl_down(mx, off, 64));
        }
        int lane = threadIdx.x & 63;
        int w = threadIdx.x >> 6;
        if (lane == 0) { smn[w] = mn; smx[w] = mx; }
        __syncthreads();
        if (threadIdx.x == 0) {
            mn = smn[0]; mx = smx[0];
            for (int j = 1; j < BLK / 64; ++j) {
                mn = fminf(mn, smn[j]);
                mx = fmaxf(mx, smx[j]);
            }
            sparams[0] = mn;
            sparams[1] = (mx - mn) + 1e-8f;  // exact fp32, same as ref
        }
        __syncthreads();
    }
    int i = blockIdx.x * blockDim.x + threadIdx.x;
    if (i >= n4) return;
    const int T = Tptr[0];
    const float mn = sparams[0];
    const float d  = sparams[1];
    const float scaleT = (float)(T - 1);

    float4 v = ((const float4*)x)[i];
    // EXACT fp32 semantics of reference: xn=(x-mn)/d; st=trunc((1-xn)*(T-1)); clip
    int st0 = (int)((1.0f - (v.x - mn) / d) * scaleT);
    int st1 = (int)((1.0f - (v.y - mn) / d) * scaleT);
    int st2 = (int)((1.0f - (v.z - mn) / d) * scaleT);
    int st3 = (int)((1.0f - (v.w - mn) / d) * scaleT);
    st0 = min(max(st0, 0), T - 1);
    st1 = min(max(st1, 0), T - 1);
    st2 = min(max(st2, 0), T - 1);
    st3 = min(max(st3, 0), T - 1);

    uchar4 o;
    o.x = (unsigned char)st0;
    o.y = (unsigned char)st1;
    o.z = (unsigned char)st2;
    o.w = (unsigned char)st3;
    ((uchar4*)st)[i] = o;
}

// ---------------- Kernel 3: register-resident t-loop writer ----------------
// Each block owns one 256-float4 (4 KB) segment of one batch image and a
// chunk of t values. Spike times are loaded ONCE into a register (uchar4
// per thread), then the inner loop is a pure plain-store stream:
// no loads, no LDS, no dependencies -- same shape as the 6.3 TB/s fill.
// Block order: segment varies fastest, so concurrently-resident blocks
// write contiguous regions of the same output plane.
__global__ void k_write(const unsigned char* __restrict__ st,
                        float* __restrict__ out,
                        int T, int TC, int CHW4, int SEGS) {
    int id = blockIdx.x;
    int sg = id % SEGS;                  // segment within plane
    int c  = (id / SEGS) % NCHUNK;       // t-chunk
    int b  = id / (SEGS * NCHUNK);       // batch

    int j = sg * BLK + threadIdx.x;      // float4 index within plane
    if (j >= CHW4) return;

    uchar4 s = ((const uchar4*)st)[(size_t)b * CHW4 + j];
    const int s0 = s.x, s1 = s.y, s2 = s.z, s3 = s.w;

    const int t0 = c * TC;
    const int t1 = min(t0 + TC, T);

    float4* __restrict__ op =
        (float4*)out + ((size_t)b * T + t0) * (size_t)CHW4 + j;

    for (int t = t0; t < t1; ++t, op += CHW4) {
        float4 o;
        o.x = (s0 == t) ? 1.0f : 0.0f;
        o.y = (s1 == t) ? 1.0f : 0.0f;
        o.z = (s2 == t) ? 1.0f : 0.0f;
        o.w = (s3 == t) ? 1.0f : 0.0f;
        *op = o;                          // plain dwordx4 store (L2 write-combine)
    }
}

extern "C" void kernel_launch(void* const* d_in, const int* in_sizes, int n_in,
                              void* d_out, int out_size, void* d_ws, size_t ws_size,
                              hipStream_t stream) {
    const float* x  = (const float*)d_in[0];
    const int* Tptr = (const int*)d_in[1];
    float* out      = (float*)d_out;

    const int n  = in_sizes[0];        // 8*3*224*224 = 1,204,224
    const int n4 = n / 4;              // 301,056
    const int B  = 8;                  // reference setup
    const int T  = out_size / n;       // 100
    const int CHW  = n / B;            // 150,528
    const int CHW4 = CHW / 4;          // 37,632

    float* partial     = (float*)d_ws;                // 2*RED_BLOCKS floats
    unsigned char* st  = (unsigned char*)d_ws + 4096; // n bytes (1.2 MB)

    k_minmax_partial<<<RED_BLOCKS, BLK, 0, stream>>>(x, n4, partial);

    int blocks = (n4 + BLK - 1) / BLK;  // 1176
    k_spiketime<<<blocks, BLK, 0, stream>>>(x, partial, Tptr, st, n4);

    const int SEGS = (CHW4 + BLK - 1) / BLK;      // 147
    const int TC   = (T + NCHUNK - 1) / NCHUNK;   // 10
    int wblocks = B * NCHUNK * SEGS;              // 11,760
    k_write<<<wblocks, BLK, 0, stream>>>(st, out, T, TC, CHW4, SEGS);
}

// Round 3
// 475.987 us; speedup vs baseline: 1.0051x; 1.0003x over previous
//
#include <hip/hip_runtime.h>
#include <cfloat>

#define BLK 256
#define RED_BLOCKS 256
#define NCHUNK 4    // t-chunks per (b,segment); T=100 -> 25 t's per block

// ---------------- Kernel 1: per-block min/max partials ----------------
__global__ void k_minmax_partial(const float* __restrict__ x, int n4,
                                 float* __restrict__ partial) {
    const float4* __restrict__ x4 = (const float4*)x;
    float mn = FLT_MAX, mx = -FLT_MAX;
    for (int i = blockIdx.x * blockDim.x + threadIdx.x; i < n4;
         i += gridDim.x * blockDim.x) {
        float4 v = x4[i];
        mn = fminf(mn, fminf(fminf(v.x, v.y), fminf(v.z, v.w)));
        mx = fmaxf(mx, fmaxf(fmaxf(v.x, v.y), fmaxf(v.z, v.w)));
    }
    for (int off = 32; off > 0; off >>= 1) {
        mn = fminf(mn, __shfl_down(mn, off, 64));
        mx = fmaxf(mx, __shfl_down(mx, off, 64));
    }
    __shared__ float smn[BLK / 64], smx[BLK / 64];
    int lane = threadIdx.x & 63;
    int w = threadIdx.x >> 6;
    if (lane == 0) { smn[w] = mn; smx[w] = mx; }
    __syncthreads();
    if (threadIdx.x == 0) {
        mn = smn[0]; mx = smx[0];
        for (int j = 1; j < BLK / 64; ++j) {
            mn = fminf(mn, smn[j]);
            mx = fmaxf(mx, smx[j]);
        }
        partial[2 * blockIdx.x]     = mn;
        partial[2 * blockIdx.x + 1] = mx;
    }
}

// ---- Kernel 2 (fused): final-reduce + spike-time + one-hot plane writer ----
// Each block: (b, t-chunk c, segment sg). It redundantly reduces the 256
// (mn,mx) pairs (identical deterministic order in every block -> bit-identical
// params), loads its 4 KB x-segment ONCE into registers, computes the four
// spike times, then streams one-hot float4 planes for its 25 t values.
// No st workspace, no extra kernel: the inner loop is a pure dependency-free
// plain-store stream (same shape as the harness's 6.3 TB/s fill).
__global__ void k_fused(const float* __restrict__ x,
                        const float* __restrict__ partial,
                        const int* __restrict__ Tptr,
                        float* __restrict__ out,
                        int TC, int CHW4, int SEGS) {
    __shared__ float smn[BLK / 64], smx[BLK / 64];
    __shared__ float sparams[2];
    {
        float mn = partial[2 * threadIdx.x];
        float mx = partial[2 * threadIdx.x + 1];
        for (int off = 32; off > 0; off >>= 1) {
            mn = fminf(mn, __shfl_down(mn, off, 64));
            mx = fmaxf(mx, __shfl_down(mx, off, 64));
        }
        int lane = threadIdx.x & 63;
        int w = threadIdx.x >> 6;
        if (lane == 0) { smn[w] = mn; smx[w] = mx; }
        __syncthreads();
        if (threadIdx.x == 0) {
            mn = smn[0]; mx = smx[0];
            for (int j = 1; j < BLK / 64; ++j) {
                mn = fminf(mn, smn[j]);
                mx = fmaxf(mx, smx[j]);
            }
            sparams[0] = mn;
            sparams[1] = (mx - mn) + 1e-8f;  // exact fp32, same as ref
        }
        __syncthreads();
    }

    const int T = Tptr[0];
    const float mn = sparams[0];
    const float d  = sparams[1];
    const float scaleT = (float)(T - 1);

    int id = blockIdx.x;
    int sg = id % SEGS;                 // segment within plane (fastest)
    int c  = (id / SEGS) % NCHUNK;      // t-chunk
    int b  = id / (SEGS * NCHUNK);      // batch

    int j = sg * BLK + threadIdx.x;     // float4 index within plane
    if (j >= CHW4) return;

    float4 v = ((const float4*)x)[(size_t)b * CHW4 + j];
    // EXACT fp32 semantics of reference: xn=(x-mn)/d; st=trunc((1-xn)*(T-1)); clip
    int st0 = (int)((1.0f - (v.x - mn) / d) * scaleT);
    int st1 = (int)((1.0f - (v.y - mn) / d) * scaleT);
    int st2 = (int)((1.0f - (v.z - mn) / d) * scaleT);
    int st3 = (int)((1.0f - (v.w - mn) / d) * scaleT);
    st0 = min(max(st0, 0), T - 1);
    st1 = min(max(st1, 0), T - 1);
    st2 = min(max(st2, 0), T - 1);
    st3 = min(max(st3, 0), T - 1);

    const int t0 = c * TC;
    const int t1 = min(t0 + TC, T);

    float4* __restrict__ op =
        (float4*)out + ((size_t)b * T + t0) * (size_t)CHW4 + j;

    for (int t = t0; t < t1; ++t, op += CHW4) {
        float4 o;
        o.x = (st0 == t) ? 1.0f : 0.0f;
        o.y = (st1 == t) ? 1.0f : 0.0f;
        o.z = (st2 == t) ? 1.0f : 0.0f;
        o.w = (st3 == t) ? 1.0f : 0.0f;
        *op = o;                          // plain dwordx4 store
    }
}

extern "C" void kernel_launch(void* const* d_in, const int* in_sizes, int n_in,
                              void* d_out, int out_size, void* d_ws, size_t ws_size,
                              hipStream_t stream) {
    const float* x  = (const float*)d_in[0];
    const int* Tptr = (const int*)d_in[1];
    float* out      = (float*)d_out;

    const int n  = in_sizes[0];        // 8*3*224*224 = 1,204,224
    const int n4 = n / 4;              // 301,056
    const int B  = 8;                  // reference setup
    const int T  = out_size / n;       // 100
    const int CHW  = n / B;            // 150,528
    const int CHW4 = CHW / 4;          // 37,632

    float* partial = (float*)d_ws;     // 2*RED_BLOCKS floats

    k_minmax_partial<<<RED_BLOCKS, BLK, 0, stream>>>(x, n4, partial);

    const int SEGS = (CHW4 + BLK - 1) / BLK;      // 147 (exact: 147*256)
    const int TC   = (T + NCHUNK - 1) / NCHUNK;   // 25
    int fblocks = B * NCHUNK * SEGS;              // 4704
    k_fused<<<fblocks, BLK, 0, stream>>>(x, partial, Tptr, out, TC, CHW4, SEGS);
}